// Round 4
// baseline (270.606 us; speedup 1.0000x reference)
//
#include <hip/hip_runtime.h>
#include <hip/hip_bf16.h>

typedef __bf16 bf16x8 __attribute__((ext_vector_type(8)));
typedef float  f32x4  __attribute__((ext_vector_type(4)));

#define LOG2E 1.4426950408889634f
#define LN2   0.6931471805599453f

__device__ __forceinline__ float rcp_(float x){
#if __has_builtin(__builtin_amdgcn_rcpf)
  return __builtin_amdgcn_rcpf(x);
#else
  return 1.0f / x;
#endif
}
__device__ __forceinline__ float ex2_(float x){
#if __has_builtin(__builtin_amdgcn_exp2f)
  return __builtin_amdgcn_exp2f(x);
#else
  return exp2f(x);
#endif
}
__device__ __forceinline__ float lg2_(float x){
#if __has_builtin(__builtin_amdgcn_logf)
  return __builtin_amdgcn_logf(x);
#else
  return log2f(x);
#endif
}
// pre-scaled activations: inputs already multiplied by -LOG2E (sigmoid) / 2*LOG2E (tanh)
__device__ __forceinline__ float sigp_(float xp){ return rcp_(1.0f + ex2_(xp)); }
__device__ __forceinline__ float tanp_(float gp){ return 1.0f - 2.0f*rcp_(1.0f + ex2_(gp)); }

__device__ __forceinline__ int pk_bf16(float lo, float hi){
  union { __bf16 h[2]; int i; } u;
  u.h[0] = (__bf16)lo; u.h[1] = (__bf16)hi;
  return u.i;
}

struct LstmArgs {
  const float* Wih[4]; const float* Whh[4];
  const float* bih[4]; const float* bhh[4];
  const float* h0[4];  const float* c0[4];
};

// ---------------------------------------------------------------------------
// Kernel A: 4 dirs x 128 batch-blocks of 16 rows, 512 threads (8 waves).
// Wave w owns unit-columns w*16..w*16+15; its 4 N-tiles are the 4 gates of
// those units (tile = g*8 + w), so lane (lc) holds gates i,f,g,o of unit
// w*16+lc for 4 batch rows -> lane-local c/h update, 40 trans/lane/step.
// Weights in registers (80 VGPR B-frags). x staged to LDS once. 2-3 blocks/CU
// co-resident (41 KiB LDS) so trans/MFMA latency overlaps across waves.
// ---------------------------------------------------------------------------
__global__ __launch_bounds__(512, 2) void lstm4_kernel(const float* __restrict__ x,
                                                       LstmArgs args,
                                                       float* __restrict__ featT)
{
  const int dir = blockIdx.x >> 7;          // 0=lr_f 1=lr_b 2=ud_f 3=ud_b
  const int b0  = (blockIdx.x & 127) * 16;
  const int tid = threadIdx.x;
  const int w   = tid >> 6;                 // wave 0..7
  const int l   = tid & 63;
  const int lc  = l & 15;
  const int lr4 = l >> 4;

  const float* __restrict__ Wih = args.Wih[dir];
  const float* __restrict__ Whh = args.Whh[dir];
  const float* __restrict__ bih = args.bih[dir];
  const float* __restrict__ bhh = args.bhh[dir];
  const float* __restrict__ h0  = args.h0[dir];
  const float* __restrict__ c0  = args.c0[dir];
  const int rev = dir & 1;
  const bool lrdir = (dir < 2);

  __shared__ __align__(16) __bf16 hcat[16 * 168];        // 5.25 KiB
  __shared__ __align__(16) __bf16 xstage[28 * 16 * 40];  // 35 KiB

  // ---- B fragments (weights): 4 gates x 5 K-steps, pre-scaled --------------
  bf16x8 bfr[4][5];
  float  bias[4];
#pragma unroll
  for (int g = 0; g < 4; ++g){
    const int grow = g*128 + w*16 + lc;            // gate-major row
    const float sc = (g == 2) ? 2.0f*LOG2E : -LOG2E;
    bias[g] = (bih[grow] + bhh[grow]) * sc;
#pragma unroll
    for (int kk = 0; kk < 4; ++kk){
      const float4* p = (const float4*)(Whh + grow*128 + kk*32 + lr4*8);
      const float4 a0 = p[0], a1 = p[1];
      bf16x8 v;
      v[0]=(__bf16)(a0.x*sc); v[1]=(__bf16)(a0.y*sc); v[2]=(__bf16)(a0.z*sc); v[3]=(__bf16)(a0.w*sc);
      v[4]=(__bf16)(a1.x*sc); v[5]=(__bf16)(a1.y*sc); v[6]=(__bf16)(a1.z*sc); v[7]=(__bf16)(a1.w*sc);
      bfr[g][kk] = v;
    }
    bf16x8 v;
    if (lr4 < 3){
      const float2* p = (const float2*)(Wih + grow*28 + lr4*8);
      const float2 a0=p[0], a1=p[1], a2=p[2], a3=p[3];
      v[0]=(__bf16)(a0.x*sc); v[1]=(__bf16)(a0.y*sc); v[2]=(__bf16)(a1.x*sc); v[3]=(__bf16)(a1.y*sc);
      v[4]=(__bf16)(a2.x*sc); v[5]=(__bf16)(a2.y*sc); v[6]=(__bf16)(a3.x*sc); v[7]=(__bf16)(a3.y*sc);
    } else {
      const float2* p = (const float2*)(Wih + grow*28 + 24);
      const float2 a0=p[0], a1=p[1];
      v[0]=(__bf16)(a0.x*sc); v[1]=(__bf16)(a0.y*sc); v[2]=(__bf16)(a1.x*sc); v[3]=(__bf16)(a1.y*sc);
      v[4]=(__bf16)0.0f; v[5]=(__bf16)0.0f; v[6]=(__bf16)0.0f; v[7]=(__bf16)0.0f;
    }
    bfr[g][4] = v;
  }

  // ---- stage whole x tile once, float4 global loads ------------------------
  for (int idx = tid; idx < 16*196; idx += 512){   // 196 = 28*7 float4 per row
    const int row = idx / 196;
    const int rem = idx - row*196;
    if (lrdir){
      const int t = rem / 7, jg = rem - 7*t;
      const float4 v = *(const float4*)&x[(b0+row)*784 + t*28 + jg*4];
      __bf16* dst = &xstage[(t*16 + row)*40 + jg*4];
      dst[0]=(__bf16)v.x; dst[1]=(__bf16)v.y; dst[2]=(__bf16)v.z; dst[3]=(__bf16)v.w;
    } else {
      const int j = rem / 7, tg = rem - 7*j;
      const float4 v = *(const float4*)&x[(b0+row)*784 + j*28 + tg*4];
      xstage[((tg*4+0)*16 + row)*40 + j] = (__bf16)v.x;
      xstage[((tg*4+1)*16 + row)*40 + j] = (__bf16)v.y;
      xstage[((tg*4+2)*16 + row)*40 + j] = (__bf16)v.z;
      xstage[((tg*4+3)*16 + row)*40 + j] = (__bf16)v.w;
    }
  }
  if (tid < 28*16){                                // zero K-pad cols 28..31
    const int t = tid >> 4, row = tid & 15;
    __bf16* p = &xstage[(t*16 + row)*40 + 28];
    p[0] = p[1] = p[2] = p[3] = (__bf16)0.0f;
  }

  // ---- initial state: each wave owns its 16 unit-cols ----------------------
  float cst[4], hfin[4];
#pragma unroll
  for (int r = 0; r < 4; ++r){
    const int row = 4*lr4 + r;
    const int col = w*16 + lc;
    cst[r] = c0[(b0+row)*128 + col];
    hcat[row*168 + col] = (__bf16)h0[(b0+row)*128 + col];
    hfin[r] = 0.0f;
  }

  // ---- 28 sequential steps -------------------------------------------------
  for (int s = 0; s < 28; ++s){
    const int t = rev ? (27 - s) : s;
    __syncthreads();

    f32x4 acc[4];
#pragma unroll
    for (int g = 0; g < 4; ++g){
      f32x4 bv = {bias[g], bias[g], bias[g], bias[g]};
      acc[g] = bv;
    }
#pragma unroll
    for (int kk = 0; kk < 5; ++kk){
      const bf16x8 a = (kk < 4)
        ? *(const bf16x8*)&hcat[lc*168 + kk*32 + lr4*8]
        : *(const bf16x8*)&xstage[(t*16 + lc)*40 + lr4*8];
#pragma unroll
      for (int g = 0; g < 4; ++g)
        acc[g] = __builtin_amdgcn_mfma_f32_16x16x32_bf16(a, bfr[g][kk], acc[g], 0, 0, 0);
    }
    __syncthreads();

#pragma unroll
    for (int r = 0; r < 4; ++r){
      const float cc = sigp_(acc[1][r])*cst[r] + sigp_(acc[0][r])*tanp_(acc[2][r]);
      cst[r] = cc;
      const float hv = sigp_(acc[3][r])*tanp_(2.0f*LOG2E*cc);
      hfin[r] = hv;
      hcat[(4*lr4 + r)*168 + w*16 + lc] = (__bf16)hv;
    }
  }

  // ---- final h -> featT[512][2048] ----------------------------------------
  {
    const int col = w*16 + lc;
    f32x4 v = {hfin[0], hfin[1], hfin[2], hfin[3]};
    *(f32x4*)&featT[(dir*128 + col)*2048 + b0 + 4*lr4] = v;
  }
}

// ---------------------------------------------------------------------------
// Kernel B: fc LSTM via MFMA, NO LDS. Gate rows ordered row = 4*unit + gate
// -> lane (grp,b) holds i,f,g,o of unit 4*mt+grp for batch b: lane-local
// update. h redistributed into the B-fragment each step via 10 parallel
// ds_bpermute (single DS round, no bank conflicts, no barrier).
// ---------------------------------------------------------------------------
__global__ __launch_bounds__(64, 1) void fc_lstm_mfma(const float* __restrict__ featT,
                                                      const float* __restrict__ Wih,
                                                      const float* __restrict__ Whh,
                                                      const float* __restrict__ bih,
                                                      const float* __restrict__ bhh,
                                                      const float* __restrict__ h0,
                                                      const float* __restrict__ c0,
                                                      float* __restrict__ out)
{
  const int l = threadIdx.x;
  const int b = l & 15;                 // batch column
  const int grp = l >> 4;
  const int bbase = blockIdx.x * 16;

  // ---- A fragments (weights, rows = 4*unit+gate, K = units 0..9) -----------
  bf16x8 afr[3];
  float bias_r[3][4], wih_r[3][4];
#pragma unroll
  for (int mt = 0; mt < 3; ++mt){
    const int row = mt*16 + b;
    const int m = row >> 2;             // unit
    const int g = row & 3;              // gate
    const float sc = (g==2) ? 2.0f*LOG2E : -LOG2E;
    bf16x8 v;
#pragma unroll
    for (int j = 0; j < 8; ++j){
      const int k = grp*8 + j;
      const float wv = (m < 10 && k < 10) ? Whh[(g*10 + m)*10 + k] * sc : 0.0f;
      v[j] = (__bf16)wv;
    }
    afr[mt] = v;
    const int mm = mt*4 + grp;
#pragma unroll
    for (int r = 0; r < 4; ++r){
      if (mm < 10){
        const float scr = (r==2) ? 2.0f*LOG2E : -LOG2E;
        bias_r[mt][r] = (bih[r*10+mm] + bhh[r*10+mm]) * scr;
        wih_r[mt][r]  = Wih[r*10+mm] * scr;
      } else { bias_r[mt][r] = 0.0f; wih_r[mt][r] = 0.0f; }
    }
  }

  // ---- state ---------------------------------------------------------------
  float c_st[3], h_st[3];
#pragma unroll
  for (int mt = 0; mt < 3; ++mt){
    const int mm = mt*4 + grp;
    c_st[mt] = (mm < 10) ? c0[(bbase+b)*10 + mm] : 0.0f;
    h_st[mt] = (mm < 10) ? h0[(bbase+b)*10 + mm] : 0.0f;
  }

  // bpermute addresses (bytes): source lane (g<<4)|b
  const int A0 = (( 0) | b) << 2;
  const int A1 = ((16) | b) << 2;
  const int A2 = ((32) | b) << 2;
  const int A3 = ((48) | b) << 2;

  // featT prefetch, depth 2
  float xa = featT[bbase + b];
  float xb = featT[2048 + bbase + b];

  for (int t = 0; t < 512; ++t){
    // ---- build B-frag: unit u -> lane grp=u>>3, elem j=u&7 ----------------
    const int h0i = __float_as_int(h_st[0]);
    const int h1i = __float_as_int(h_st[1]);
    const int h2i = __float_as_int(h_st[2]);
    const float v0 = __int_as_float(__builtin_amdgcn_ds_bpermute(A0, h0i));
    const float v1 = __int_as_float(__builtin_amdgcn_ds_bpermute(A1, h0i));
    const float v2 = __int_as_float(__builtin_amdgcn_ds_bpermute(A2, h0i));
    const float v3 = __int_as_float(__builtin_amdgcn_ds_bpermute(A3, h0i));
    const float v4 = __int_as_float(__builtin_amdgcn_ds_bpermute(A0, h1i));
    const float v5 = __int_as_float(__builtin_amdgcn_ds_bpermute(A1, h1i));
    const float v6 = __int_as_float(__builtin_amdgcn_ds_bpermute(A2, h1i));
    const float v7 = __int_as_float(__builtin_amdgcn_ds_bpermute(A3, h1i));
    const float v8 = __int_as_float(__builtin_amdgcn_ds_bpermute(A0, h2i));
    const float v9 = __int_as_float(__builtin_amdgcn_ds_bpermute(A1, h2i));

    const int pk01 = pk_bf16(v0, v1);
    const int pk23 = pk_bf16(v2, v3);
    const int pk45 = pk_bf16(v4, v5);
    const int pk67 = pk_bf16(v6, v7);
    const int pk89 = pk_bf16(v8, v9);

    union { int w[4]; bf16x8 v; } bu;
    bu.w[0] = (grp == 0) ? pk01 : ((grp == 1) ? pk89 : 0);
    bu.w[1] = (grp == 0) ? pk23 : 0;
    bu.w[2] = (grp == 0) ? pk45 : 0;
    bu.w[3] = (grp == 0) ? pk67 : 0;

    const float xt = xa;
    xa = xb;
    if (t + 2 < 512) xb = featT[(t+2)*2048 + bbase + b];

    f32x4 acc[3];
#pragma unroll
    for (int mt = 0; mt < 3; ++mt){
#pragma unroll
      for (int r = 0; r < 4; ++r) acc[mt][r] = bias_r[mt][r] + wih_r[mt][r]*xt;
      acc[mt] = __builtin_amdgcn_mfma_f32_16x16x32_bf16(afr[mt], bu.v, acc[mt], 0, 0, 0);
    }

#pragma unroll
    for (int mt = 0; mt < 3; ++mt){
      const float cc = sigp_(acc[mt][1])*c_st[mt] + sigp_(acc[mt][0])*tanp_(acc[mt][2]);
      c_st[mt] = cc;
      h_st[mt] = sigp_(acc[mt][3])*tanp_(2.0f*LOG2E*cc);
    }
  }

  // ---- log-softmax over units 0..9 of each batch column --------------------
  float pm = -3.0e38f;
#pragma unroll
  for (int mt = 0; mt < 3; ++mt){ const int mm = mt*4+grp; if (mm < 10) pm = fmaxf(pm, h_st[mt]); }
  pm = fmaxf(pm, __shfl_xor(pm, 16, 64));
  pm = fmaxf(pm, __shfl_xor(pm, 32, 64));
  float es = 0.0f;
#pragma unroll
  for (int mt = 0; mt < 3; ++mt){ const int mm = mt*4+grp; if (mm < 10) es += ex2_(LOG2E*(h_st[mt]-pm)); }
  es += __shfl_xor(es, 16, 64);
  es += __shfl_xor(es, 32, 64);
  const float lse = LN2 * lg2_(es);
#pragma unroll
  for (int mt = 0; mt < 3; ++mt){
    const int mm = mt*4 + grp;
    if (mm < 10) out[(bbase+b)*10 + mm] = h_st[mt] - pm - lse;
  }
}

extern "C" void kernel_launch(void* const* d_in, const int* in_sizes, int n_in,
                              void* d_out, int out_size, void* d_ws, size_t ws_size,
                              hipStream_t stream)
{
  const float* x = (const float*)d_in[0];
  LstmArgs a;
  const int base[4] = {1, 5, 9, 13};   // lr_f, lr_b, ud_f, ud_b
  for (int d = 0; d < 4; ++d){
    a.Wih[d] = (const float*)d_in[base[d] + 0];
    a.Whh[d] = (const float*)d_in[base[d] + 1];
    a.bih[d] = (const float*)d_in[base[d] + 2];
    a.bhh[d] = (const float*)d_in[base[d] + 3];
  }
  const float* h0lr = (const float*)d_in[21];
  const float* c0lr = (const float*)d_in[22];
  const float* h0ud = (const float*)d_in[23];
  const float* c0ud = (const float*)d_in[24];
  a.h0[0] = h0lr;               a.c0[0] = c0lr;
  a.h0[1] = h0lr + 2048*128;    a.c0[1] = c0lr + 2048*128;
  a.h0[2] = h0ud;               a.c0[2] = c0ud;
  a.h0[3] = h0ud + 2048*128;    a.c0[3] = c0ud + 2048*128;

  float* featT = (float*)d_ws;   // [512][2048] f32 = 4 MiB

  lstm4_kernel<<<512, 512, 0, stream>>>(x, a, featT);
  fc_lstm_mfma<<<128, 64, 0, stream>>>(featT,
      (const float*)d_in[17], (const float*)d_in[18],
      (const float*)d_in[19], (const float*)d_in[20],
      (const float*)d_in[25], (const float*)d_in[26],
      (float*)d_out);
}

// Round 5
// 142.053 us; speedup vs baseline: 1.9050x; 1.9050x over previous
//
#include <hip/hip_runtime.h>
#include <hip/hip_bf16.h>

typedef __bf16 bf16x8 __attribute__((ext_vector_type(8)));
typedef float  f32x4  __attribute__((ext_vector_type(4)));

#define LOG2E 1.4426950408889634f
#define LN2   0.6931471805599453f

__device__ __forceinline__ float rcp_(float x){
#if __has_builtin(__builtin_amdgcn_rcpf)
  return __builtin_amdgcn_rcpf(x);
#else
  return 1.0f / x;
#endif
}
__device__ __forceinline__ float ex2_(float x){
#if __has_builtin(__builtin_amdgcn_exp2f)
  return __builtin_amdgcn_exp2f(x);
#else
  return exp2f(x);
#endif
}
__device__ __forceinline__ float lg2_(float x){
#if __has_builtin(__builtin_amdgcn_logf)
  return __builtin_amdgcn_logf(x);
#else
  return log2f(x);
#endif
}
// pre-scaled activations: inputs pre-multiplied by -LOG2E (sigmoid) / 2*LOG2E (tanh)
__device__ __forceinline__ float sigp_(float xp){ return rcp_(1.0f + ex2_(xp)); }
__device__ __forceinline__ float tanp_(float gp){ return 1.0f - 2.0f*rcp_(1.0f + ex2_(gp)); }

struct LstmArgs {
  const float* Wih[4]; const float* Whh[4];
  const float* bih[4]; const float* bhh[4];
  const float* h0[4];  const float* c0[4];
};

// ---------------------------------------------------------------------------
// pack_weights: one-time conversion of the 4 bi-LSTM weight sets into
// fragment-lane-ordered, pre-scaled bf16x8 blobs + pre-scaled biases, so
// lstm4's preamble is 20 perfectly-coalesced 16B loads per lane.
// wpack[((d*8+w)*4+g)*5+kk][lane] ; bpack[d*512 + grow]
// ---------------------------------------------------------------------------
__global__ void pack_weights(LstmArgs args, bf16x8* __restrict__ wpack,
                             float* __restrict__ bpack)
{
  const int idx = blockIdx.x*256 + threadIdx.x;      // 40960 total
  if (idx >= 4*8*4*5*64) return;
  const int lane = idx & 63;
  int r = idx >> 6;
  const int kk = r % 5; r /= 5;
  const int g  = r & 3; r >>= 2;
  const int w  = r & 7;
  const int d  = r >> 3;
  const int lc = lane & 15, lr4 = lane >> 4;
  const int grow = g*128 + w*16 + lc;
  const float sc = (g == 2) ? 2.0f*LOG2E : -LOG2E;

  bf16x8 v;
  if (kk < 4){
    const float* p = args.Whh[d] + grow*128 + kk*32 + lr4*8;
#pragma unroll
    for (int j = 0; j < 8; ++j) v[j] = (__bf16)(p[j] * sc);
  } else {
#pragma unroll
    for (int j = 0; j < 8; ++j){
      const int xi = lr4*8 + j;
      v[j] = (xi < 28) ? (__bf16)(args.Wih[d][grow*28 + xi] * sc) : (__bf16)0.0f;
    }
  }
  wpack[idx] = v;
  if (kk == 0 && lr4 == 0)
    bpack[d*512 + grow] = (args.bih[d][grow] + args.bhh[d][grow]) * sc;
}

// ---------------------------------------------------------------------------
// Kernel A: 4 dirs x 64 batch-blocks of 32 rows, 8 waves (512 thr).
// Wave w owns unit-cols w*16..+15 (4 gate-tiles); 2 batch m-tiles.
// 256 blocks exactly = 1/CU, single dispatch round. Weights from wpack
// (coalesced). x staged once to LDS. featB written bf16 [batch][512].
// ---------------------------------------------------------------------------
__global__ __launch_bounds__(512, 2) void lstm4_kernel(const float* __restrict__ x,
                                                       LstmArgs args,
                                                       const bf16x8* __restrict__ wpack,
                                                       const float* __restrict__ bpack,
                                                       __bf16* __restrict__ featB)
{
  const int dir = blockIdx.x >> 6;          // 0=lr_f 1=lr_b 2=ud_f 3=ud_b
  const int b0  = (blockIdx.x & 63) * 32;
  const int tid = threadIdx.x;
  const int w   = tid >> 6;                 // wave 0..7
  const int l   = tid & 63;
  const int lc  = l & 15;
  const int lr4 = l >> 4;

  const float* __restrict__ h0 = args.h0[dir];
  const float* __restrict__ c0 = args.c0[dir];
  const int rev = dir & 1;
  const bool lrdir = (dir < 2);

  __shared__ __align__(16) __bf16 hcat[32 * 168];        // 10.5 KiB
  __shared__ __align__(16) __bf16 xstage[28 * 32 * 40];  // 70 KiB

  // ---- B fragments: coalesced 16B loads from wpack ------------------------
  bf16x8 bfr[4][5];
  float  bias[4];
  {
    const bf16x8* wp = wpack + (dir*8 + w)*4*5*64;
#pragma unroll
    for (int g = 0; g < 4; ++g){
#pragma unroll
      for (int kk = 0; kk < 5; ++kk)
        bfr[g][kk] = wp[(g*5 + kk)*64 + l];
      bias[g] = bpack[dir*512 + g*128 + w*16 + lc];
    }
  }

  // ---- stage whole x tile once, float4 global loads ------------------------
  for (int idx = tid; idx < 32*196; idx += 512){   // 196 = 28*7 float4 per row
    const int row = idx / 196;
    const int rem = idx - row*196;
    if (lrdir){
      const int t = rem / 7, jg = rem - 7*t;
      const float4 v = *(const float4*)&x[(b0+row)*784 + t*28 + jg*4];
      __bf16* dst = &xstage[(t*32 + row)*40 + jg*4];
      dst[0]=(__bf16)v.x; dst[1]=(__bf16)v.y; dst[2]=(__bf16)v.z; dst[3]=(__bf16)v.w;
    } else {
      const int j = rem / 7, tg = rem - 7*j;
      const float4 v = *(const float4*)&x[(b0+row)*784 + j*28 + tg*4];
      xstage[((tg*4+0)*32 + row)*40 + j] = (__bf16)v.x;
      xstage[((tg*4+1)*32 + row)*40 + j] = (__bf16)v.y;
      xstage[((tg*4+2)*32 + row)*40 + j] = (__bf16)v.z;
      xstage[((tg*4+3)*32 + row)*40 + j] = (__bf16)v.w;
    }
  }
  for (int idx = tid; idx < 28*32; idx += 512){    // zero K-pad cols 28..31
    const int t = idx >> 5, row = idx & 31;
    __bf16* p = &xstage[(t*32 + row)*40 + 28];
    p[0] = p[1] = p[2] = p[3] = (__bf16)0.0f;
  }

  // ---- initial state -------------------------------------------------------
  float cst[2][4], hfin[2][4];
#pragma unroll
  for (int m = 0; m < 2; ++m)
#pragma unroll
  for (int r = 0; r < 4; ++r){
    const int row = 16*m + 4*lr4 + r;
    const int col = w*16 + lc;
    cst[m][r] = c0[(b0+row)*128 + col];
    hcat[row*168 + col] = (__bf16)h0[(b0+row)*128 + col];
    hfin[m][r] = 0.0f;
  }

  // ---- 28 sequential steps -------------------------------------------------
  for (int s = 0; s < 28; ++s){
    const int t = rev ? (27 - s) : s;
    __syncthreads();

    f32x4 acc[2][4];
#pragma unroll
    for (int m = 0; m < 2; ++m)
#pragma unroll
    for (int g = 0; g < 4; ++g){
      f32x4 bv = {bias[g], bias[g], bias[g], bias[g]};
      acc[m][g] = bv;
    }
#pragma unroll
    for (int m = 0; m < 2; ++m){
#pragma unroll
      for (int kk = 0; kk < 5; ++kk){
        const bf16x8 a = (kk < 4)
          ? *(const bf16x8*)&hcat[(16*m + lc)*168 + kk*32 + lr4*8]
          : *(const bf16x8*)&xstage[(t*32 + 16*m + lc)*40 + lr4*8];
#pragma unroll
        for (int g = 0; g < 4; ++g)
          acc[m][g] = __builtin_amdgcn_mfma_f32_16x16x32_bf16(a, bfr[g][kk], acc[m][g], 0, 0, 0);
      }
    }
    __syncthreads();

#pragma unroll
    for (int m = 0; m < 2; ++m)
#pragma unroll
    for (int r = 0; r < 4; ++r){
      const float cc = sigp_(acc[m][1][r])*cst[m][r] + sigp_(acc[m][0][r])*tanp_(acc[m][2][r]);
      cst[m][r] = cc;
      const float hv = sigp_(acc[m][3][r])*tanp_(2.0f*LOG2E*cc);
      hfin[m][r] = hv;
      hcat[(16*m + 4*lr4 + r)*168 + w*16 + lc] = (__bf16)hv;
    }
  }

  // ---- final h -> featB[batch][512] bf16 ----------------------------------
  {
    const int fcol = dir*128 + w*16 + lc;
#pragma unroll
    for (int m = 0; m < 2; ++m)
#pragma unroll
    for (int r = 0; r < 4; ++r)
      featB[(b0 + 16*m + 4*lr4 + r)*512 + fcol] = (__bf16)hfin[m][r];
  }
}

// ---------------------------------------------------------------------------
// Kernel B: fc LSTM, one wave per batch element. Lanes = gate-rows 4u+g
// (40 active). Per step: xt via readlane from a 64-step coalesced window;
// 11-FMA dot with SGPR h; quad_perm DPP gathers i/f/g/o; h back to SGPRs
// via 10 readlanes. No LDS, no DS pipe, no barriers. 2048 waves = 8/CU.
// ---------------------------------------------------------------------------
__global__ __launch_bounds__(256) void fc_lstm_wave(const ushort* __restrict__ featB,
                                                    const float* __restrict__ Wih,
                                                    const float* __restrict__ Whh,
                                                    const float* __restrict__ bih,
                                                    const float* __restrict__ bhh,
                                                    const float* __restrict__ h0,
                                                    const float* __restrict__ c0,
                                                    float* __restrict__ out)
{
  const int tid = threadIdx.x;
  const int l   = tid & 63;
  const int e   = blockIdx.x*4 + (tid >> 6);
  const int u   = l >> 2;                    // unit (valid < 10)
  const int g   = l & 3;                     // gate 0=i 1=f 2=g 3=o
  const int uc  = (u < 10) ? u : 9;
  const bool valid = (u < 10);
  const float sc = (g == 2) ? 2.0f*LOG2E : -LOG2E;
  const int row = g*10 + uc;

  float wh[10];
#pragma unroll
  for (int m = 0; m < 10; ++m) wh[m] = valid ? Whh[row*10 + m]*sc : 0.0f;
  const float wx   = valid ? Wih[row]*sc : 0.0f;
  const float bia  = valid ? (bih[row] + bhh[row])*sc : 0.0f;
  const float actA = (g == 2) ? 1.0f : 0.0f;
  const float actB = (g == 2) ? -2.0f : 1.0f;

  float c = valid ? c0[e*10 + uc] : 0.0f;
  float hlast = valid ? h0[e*10 + uc] : 0.0f;

  int hb = __float_as_int(hlast);
  float sh0 = __int_as_float(__builtin_amdgcn_readlane(hb,  0));
  float sh1 = __int_as_float(__builtin_amdgcn_readlane(hb,  4));
  float sh2 = __int_as_float(__builtin_amdgcn_readlane(hb,  8));
  float sh3 = __int_as_float(__builtin_amdgcn_readlane(hb, 12));
  float sh4 = __int_as_float(__builtin_amdgcn_readlane(hb, 16));
  float sh5 = __int_as_float(__builtin_amdgcn_readlane(hb, 20));
  float sh6 = __int_as_float(__builtin_amdgcn_readlane(hb, 24));
  float sh7 = __int_as_float(__builtin_amdgcn_readlane(hb, 28));
  float sh8 = __int_as_float(__builtin_amdgcn_readlane(hb, 32));
  float sh9 = __int_as_float(__builtin_amdgcn_readlane(hb, 36));

  const ushort* fB = featB + e*512;
  int vxc = (int)fB[l];            // steps 0..63 (bf16 bits, zero-extended)
  int vxn = (int)fB[64 + l];       // steps 64..127

  for (int win = 0; win < 8; ++win){
#pragma unroll 4
    for (int j = 0; j < 64; ++j){
      const float xs = __int_as_float(__builtin_amdgcn_readlane(vxc, j) << 16);
      float a0 = __builtin_fmaf(wx, xs, bia);
      a0 = __builtin_fmaf(wh[0], sh0, a0);
      float a1 = wh[1]*sh1;
      a0 = __builtin_fmaf(wh[2], sh2, a0); a1 = __builtin_fmaf(wh[3], sh3, a1);
      a0 = __builtin_fmaf(wh[4], sh4, a0); a1 = __builtin_fmaf(wh[5], sh5, a1);
      a0 = __builtin_fmaf(wh[6], sh6, a0); a1 = __builtin_fmaf(wh[7], sh7, a1);
      a0 = __builtin_fmaf(wh[8], sh8, a0); a1 = __builtin_fmaf(wh[9], sh9, a1);
      const float acc = a0 + a1;
      const float rc  = rcp_(1.0f + ex2_(acc));
      const float val = __builtin_fmaf(actB, rc, actA);
      const int   vi  = __float_as_int(val);
      const float si  = __int_as_float(__builtin_amdgcn_mov_dpp(vi, 0x00, 0xF, 0xF, false));
      const float sf  = __int_as_float(__builtin_amdgcn_mov_dpp(vi, 0x55, 0xF, 0xF, false));
      const float tg  = __int_as_float(__builtin_amdgcn_mov_dpp(vi, 0xAA, 0xF, 0xF, false));
      const float so  = __int_as_float(__builtin_amdgcn_mov_dpp(vi, 0xFF, 0xF, 0xF, false));
      c = __builtin_fmaf(sf, c, si*tg);
      const float tc = __builtin_fmaf(-2.0f, rcp_(1.0f + ex2_(2.0f*LOG2E*c)), 1.0f);
      const float h  = so*tc;
      hlast = h;
      const int hbi = __float_as_int(h);
      sh0 = __int_as_float(__builtin_amdgcn_readlane(hbi,  0));
      sh1 = __int_as_float(__builtin_amdgcn_readlane(hbi,  4));
      sh2 = __int_as_float(__builtin_amdgcn_readlane(hbi,  8));
      sh3 = __int_as_float(__builtin_amdgcn_readlane(hbi, 12));
      sh4 = __int_as_float(__builtin_amdgcn_readlane(hbi, 16));
      sh5 = __int_as_float(__builtin_amdgcn_readlane(hbi, 20));
      sh6 = __int_as_float(__builtin_amdgcn_readlane(hbi, 24));
      sh7 = __int_as_float(__builtin_amdgcn_readlane(hbi, 28));
      sh8 = __int_as_float(__builtin_amdgcn_readlane(hbi, 32));
      sh9 = __int_as_float(__builtin_amdgcn_readlane(hbi, 36));
    }
    vxc = vxn;
    if (win < 6) vxn = (int)fB[(win+2)*64 + l];
  }

  // ---- log-softmax over units 0..9 ----------------------------------------
  float mx = sh0;
  mx = fmaxf(mx, sh1); mx = fmaxf(mx, sh2); mx = fmaxf(mx, sh3);
  mx = fmaxf(mx, sh4); mx = fmaxf(mx, sh5); mx = fmaxf(mx, sh6);
  mx = fmaxf(mx, sh7); mx = fmaxf(mx, sh8); mx = fmaxf(mx, sh9);
  float es = ex2_(LOG2E*(sh0 - mx));
  es += ex2_(LOG2E*(sh1 - mx)); es += ex2_(LOG2E*(sh2 - mx));
  es += ex2_(LOG2E*(sh3 - mx)); es += ex2_(LOG2E*(sh4 - mx));
  es += ex2_(LOG2E*(sh5 - mx)); es += ex2_(LOG2E*(sh6 - mx));
  es += ex2_(LOG2E*(sh7 - mx)); es += ex2_(LOG2E*(sh8 - mx));
  es += ex2_(LOG2E*(sh9 - mx));
  const float lse = LN2 * lg2_(es);
  if (valid && g == 0) out[e*10 + u] = hlast - mx - lse;
}

extern "C" void kernel_launch(void* const* d_in, const int* in_sizes, int n_in,
                              void* d_out, int out_size, void* d_ws, size_t ws_size,
                              hipStream_t stream)
{
  const float* x = (const float*)d_in[0];
  LstmArgs a;
  const int base[4] = {1, 5, 9, 13};   // lr_f, lr_b, ud_f, ud_b
  for (int d = 0; d < 4; ++d){
    a.Wih[d] = (const float*)d_in[base[d] + 0];
    a.Whh[d] = (const float*)d_in[base[d] + 1];
    a.bih[d] = (const float*)d_in[base[d] + 2];
    a.bhh[d] = (const float*)d_in[base[d] + 3];
  }
  const float* h0lr = (const float*)d_in[21];
  const float* c0lr = (const float*)d_in[22];
  const float* h0ud = (const float*)d_in[23];
  const float* c0ud = (const float*)d_in[24];
  a.h0[0] = h0lr;               a.c0[0] = c0lr;
  a.h0[1] = h0lr + 2048*128;    a.c0[1] = c0lr + 2048*128;
  a.h0[2] = h0ud;               a.c0[2] = c0ud;
  a.h0[3] = h0ud + 2048*128;    a.c0[3] = c0ud + 2048*128;

  char* ws = (char*)d_ws;
  __bf16* featB = (__bf16*)ws;                          // 2048*512*2 = 2 MiB
  bf16x8* wpack = (bf16x8*)(ws + (2u<<20));             // 40960*16 = 640 KiB
  float*  bpack = (float*)(ws + (2u<<20) + 655360u);    // 2048*4 = 8 KiB

  pack_weights<<<160, 256, 0, stream>>>(a, wpack, bpack);
  lstm4_kernel<<<256, 512, 0, stream>>>(x, a, wpack, bpack, featB);
  fc_lstm_wave<<<512, 256, 0, stream>>>((const ushort*)featB,
      (const float*)d_in[17], (const float*)d_in[18],
      (const float*)d_in[19], (const float*)d_in[20],
      (const float*)d_in[25], (const float*)d_in[26],
      (float*)d_out);
}